// Round 1
// baseline (98.297 us; speedup 1.0000x reference)
//
#include <hip/hip_runtime.h>

// IDWT (Haar inverse) — depth-to-space r=2 with 4-tap channel mix.
// Input  x: (B=4, H=256, W=256, C=256) fp32, NHWC contiguous.
// Output y: (B, 2H=512, 2W=512, oc=64) fp32.
//
// out[b,2h+0,2w+0,c] = 0.5*(x1 - x2 - x3 + x4)
// out[b,2h+1,2w+0,c] = 0.5*(x1 + x2 - x3 - x4)
// out[b,2h+0,2w+1,c] = 0.5*(x1 - x2 + x3 - x4)
// out[b,2h+1,2w+1,c] = 0.5*(x1 + x2 + x3 + x4)
// where xk = x[b,h,w,(k-1)*64 + c].

__global__ __launch_bounds__(256) void idwt_kernel(const float* __restrict__ x,
                                                   float* __restrict__ out) {
    // Each thread: one (b,h,w) pixel x one group of 4 channels (c4 in [0,16)).
    // Total threads = 4*256*256*16 = 4,194,304.
    const int tid = blockIdx.x * blockDim.x + threadIdx.x;
    const int c4  = tid & 15;          // channel group (4 floats each)
    const int pix = tid >> 4;          // flat (b,h,w), 0 .. 4*256*256-1
    const int w   = pix & 255;
    const int h   = (pix >> 8) & 255;
    const int b   = pix >> 16;

    const float4* __restrict__ xin =
        reinterpret_cast<const float4*>(x + (size_t)pix * 256) + c4;

    // x + pix*256 + c4*4, groups at +64/+128/+192 floats = +16 float4s
    const float4 a1 = xin[0];
    const float4 a2 = xin[16];
    const float4 a3 = xin[32];
    const float4 a4 = xin[48];

    float4 h01, h02, h03, h04;
    {
        // scale by 0.5 folded into the combination
        const float s = 0.5f;
#define COMB(F, e)                                                \
        F.e = s * (a1.e) ;                                        \
        h01.e = s*(a1.e - a2.e - a3.e + a4.e);                    \
        h02.e = s*(a1.e + a2.e - a3.e - a4.e);                    \
        h03.e = s*(a1.e - a2.e + a3.e - a4.e);                    \
        h04.e = s*(a1.e + a2.e + a3.e + a4.e);
        // (first line of macro is dead; kept minimal below instead)
#undef COMB
#define MIX(e)                                                    \
        h01.e = s*(a1.e - a2.e - a3.e + a4.e);                    \
        h02.e = s*(a1.e + a2.e - a3.e - a4.e);                    \
        h03.e = s*(a1.e - a2.e + a3.e - a4.e);                    \
        h04.e = s*(a1.e + a2.e + a3.e + a4.e);
        MIX(x) MIX(y) MIX(z) MIX(w)
#undef MIX
    }

    // Output geometry: (B, 512, 512, 64)
    const int r0 = 2 * h;
    const int c0 = 2 * w;
    float4* __restrict__ o00 = reinterpret_cast<float4*>(
        out + (((size_t)b * 512 + r0) * 512 + c0) * 64) + c4;
    float4* __restrict__ o01 = o00 + 16;          // (r0,   c0+1): +64 floats
    float4* __restrict__ o10 = reinterpret_cast<float4*>(
        out + (((size_t)b * 512 + r0 + 1) * 512 + c0) * 64) + c4;
    float4* __restrict__ o11 = o10 + 16;          // (r0+1, c0+1)

    o00[0] = h01;   // out[2h,   2w  ]
    o10[0] = h02;   // out[2h+1, 2w  ]
    o01[0] = h03;   // out[2h,   2w+1]
    o11[0] = h04;   // out[2h+1, 2w+1]
}

extern "C" void kernel_launch(void* const* d_in, const int* in_sizes, int n_in,
                              void* d_out, int out_size, void* d_ws, size_t ws_size,
                              hipStream_t stream) {
    const float* x = (const float*)d_in[0];
    float* out = (float*)d_out;

    const int total_threads = 4 * 256 * 256 * 16;   // 4,194,304
    const int block = 256;
    const int grid = total_threads / block;         // 16,384
    idwt_kernel<<<grid, block, 0, stream>>>(x, out);
}

// Round 3
// 85.669 us; speedup vs baseline: 1.1474x; 1.1474x over previous
//
#include <hip/hip_runtime.h>

// IDWT (Haar inverse) — depth-to-space r=2 with 4-tap channel mix.
// Input  x: (B=4, H=256, W=256, C=256) fp32, NHWC contiguous.
// Output y: (B, 2H=512, 2W=512, oc=64) fp32.
//
// out[b,2h+0,2w+0,c] = 0.5*(x1 - x2 - x3 + x4)   (h01)
// out[b,2h+1,2w+0,c] = 0.5*(x1 + x2 - x3 - x4)   (h02)
// out[b,2h+0,2w+1,c] = 0.5*(x1 - x2 + x3 - x4)   (h03)
// out[b,2h+1,2w+1,c] = 0.5*(x1 + x2 + x3 + x4)   (h04)
//
// Mapping: one thread per (b, h, output-col o, c4). Each thread reads the 4
// groups of input pixel w=o>>1 (lane pairs share addresses -> merged by the
// coalescer) and writes one float4 to the even output row and one to the odd
// output row. Every wave store is 1KB dense & aligned.
// even = 0.5*((a1-a2) + sc*(a3-a4)),  odd = 0.5*((a1+a2) + sc*(a3+a4)),
// sc = (o&1) ? +1 : -1.

typedef float f32x4 __attribute__((ext_vector_type(4)));

__global__ __launch_bounds__(256) void idwt_kernel(const float* __restrict__ x,
                                                   float* __restrict__ out) {
    const int t  = blockIdx.x * blockDim.x + threadIdx.x;
    const int c4 = t & 15;            // float4 index within 64-ch group
    const int o  = (t >> 4) & 511;    // output column, 0..511
    const int h  = (t >> 13) & 255;   // input row
    const int b  = t >> 21;           // batch
    const int w  = o >> 1;            // input column
    const float sc = (o & 1) ? 1.0f : -1.0f;

    const f32x4* __restrict__ xin = reinterpret_cast<const f32x4*>(
        x + (size_t)(((b * 256 + h) * 256 + w)) * 256) + c4;

    const f32x4 a1 = __builtin_nontemporal_load(xin + 0);
    const f32x4 a2 = __builtin_nontemporal_load(xin + 16);
    const f32x4 a3 = __builtin_nontemporal_load(xin + 32);
    const f32x4 a4 = __builtin_nontemporal_load(xin + 48);

    const f32x4 ev = 0.5f * ((a1 - a2) + sc * (a3 - a4));
    const f32x4 od = 0.5f * ((a1 + a2) + sc * (a3 + a4));

    // Output rows 2h and 2h+1; flat float4 index within a row = o*16 + c4.
    const size_t row_even = ((size_t)(b * 512 + 2 * h) * 512) * 16;  // in float4s
    f32x4* __restrict__ oe = reinterpret_cast<f32x4*>(out) + row_even + (o * 16 + c4);
    f32x4* __restrict__ oo = oe + 512 * 16;   // next row: 512 cols * 16 float4

    __builtin_nontemporal_store(ev, oe);
    __builtin_nontemporal_store(od, oo);
}

extern "C" void kernel_launch(void* const* d_in, const int* in_sizes, int n_in,
                              void* d_out, int out_size, void* d_ws, size_t ws_size,
                              hipStream_t stream) {
    const float* x = (const float*)d_in[0];
    float* out = (float*)d_out;

    const int total_threads = 4 * 256 * 512 * 16;   // 8,388,608
    const int block = 256;
    const int grid = total_threads / block;         // 32,768
    idwt_kernel<<<grid, block, 0, stream>>>(x, out);
}